// Round 1
// baseline (93.435 us; speedup 1.0000x reference)
//
#include <hip/hip_runtime.h>
#include <cstdint>

#define NB 32
#define NC 512
#define NQ 64
#define ND 512
#define CR 64          // context rows per block in k1

// LDS float offsets (k1)
#define CMT_OFF 0      // [64][68] ctx*w_m, transposed [k][c]
#define QT_OFF  4352   // [64][68] query, transposed [k][q]  (GEMM2 reuses 0..8192 as qs[64][128])
#define AT_OFF  8704   // [64][68] softmax probs, transposed [q][c]
#define SCS_OFF 13056  // [64] s_c
#define SQS_OFF 13120  // [64] s_q
#define LDS_FLOATS 13184

__global__ __launch_bounds__(256) void k1_main(
    const float* __restrict__ ctx, const float* __restrict__ qry,
    const float* __restrict__ W, float* __restrict__ G, float* __restrict__ m_ws)
{
  __shared__ float lds[LDS_FLOATS];
  const int t  = threadIdx.x;
  const int b  = blockIdx.x >> 3;          // 8 blocks per batch
  const int c0 = (blockIdx.x & 7) * CR;

  // GEMM1 output mapping: thread owns S[2 c][8 q]
  const int qg = t & 7;        // q group: q = qg*8 + j
  const int cp = t >> 3;       // c pair:  c = c0 + cp*2 + i
  // loader mapping: row lc, quarter lj
  const int lc = t >> 2, lj = t & 3;

  const float* ctxRow = ctx + ((size_t)(b*NC + c0 + lc))*ND;
  const float* qryRow = qry + ((size_t)(b*NQ + lc))*ND;

  float acc[2][8];
  #pragma unroll
  for (int i = 0; i < 2; ++i)
    #pragma unroll
    for (int j = 0; j < 8; ++j) acc[i][j] = 0.f;
  float scp = 0.f, sqp = 0.f;

  // ---------------- GEMM1: S = (ctx*w_m) @ query^T, K = 512 in 8 chunks ----------------
  for (int kc = 0; kc < 8; ++kc) {
    const int d0 = kc * 64;
    __syncthreads();
    #pragma unroll
    for (int v = 0; v < 4; ++v) {
      const int dl = lj*16 + v*4;
      const int d  = d0 + dl;
      const float4 cv = *(const float4*)(ctxRow + d);
      const float4 qv = *(const float4*)(qryRow + d);
      const float4 wc = *(const float4*)(W + d);
      const float4 wq = *(const float4*)(W + ND + d);
      const float4 wm = *(const float4*)(W + 2*ND + d);
      scp += cv.x*wc.x + cv.y*wc.y + cv.z*wc.z + cv.w*wc.w;
      sqp += qv.x*wq.x + qv.y*wq.y + qv.z*wq.z + qv.w*wq.w;
      lds[CMT_OFF + (dl+0)*68 + lc] = cv.x*wm.x;
      lds[CMT_OFF + (dl+1)*68 + lc] = cv.y*wm.y;
      lds[CMT_OFF + (dl+2)*68 + lc] = cv.z*wm.z;
      lds[CMT_OFF + (dl+3)*68 + lc] = cv.w*wm.w;
      lds[QT_OFF + (dl+0)*68 + lc] = qv.x;
      lds[QT_OFF + (dl+1)*68 + lc] = qv.y;
      lds[QT_OFF + (dl+2)*68 + lc] = qv.z;
      lds[QT_OFF + (dl+3)*68 + lc] = qv.w;
    }
    __syncthreads();
    #pragma unroll 4
    for (int k = 0; k < 64; ++k) {
      const float2 cm = *(const float2*)&lds[CMT_OFF + k*68 + cp*2];
      const float4 qa = *(const float4*)&lds[QT_OFF + k*68 + qg*8];
      const float4 qb = *(const float4*)&lds[QT_OFF + k*68 + qg*8 + 4];
      acc[0][0] += cm.x*qa.x; acc[1][0] += cm.y*qa.x;
      acc[0][1] += cm.x*qa.y; acc[1][1] += cm.y*qa.y;
      acc[0][2] += cm.x*qa.z; acc[1][2] += cm.y*qa.z;
      acc[0][3] += cm.x*qa.w; acc[1][3] += cm.y*qa.w;
      acc[0][4] += cm.x*qb.x; acc[1][4] += cm.y*qb.x;
      acc[0][5] += cm.x*qb.y; acc[1][5] += cm.y*qb.y;
      acc[0][6] += cm.x*qb.z; acc[1][6] += cm.y*qb.z;
      acc[0][7] += cm.x*qb.w; acc[1][7] += cm.y*qb.w;
    }
  }

  // s_c / s_q: reduce the 4 loader partials per row
  scp += __shfl_xor(scp, 1, 4); scp += __shfl_xor(scp, 2, 4);
  sqp += __shfl_xor(sqp, 1, 4); sqp += __shfl_xor(sqp, 2, 4);
  if (lj == 0) { lds[SCS_OFF + lc] = scp; lds[SQS_OFF + lc] = sqp; }
  __syncthreads();

  // ---------------- softmax over q (row of 64, spread over 8 lanes x 8 vals) ----------------
  {
    const float sc0 = lds[SCS_OFF + cp*2 + 0];
    const float sc1 = lds[SCS_OFF + cp*2 + 1];
    float sval[2][8];
    #pragma unroll
    for (int j = 0; j < 8; ++j) {
      const float sq = lds[SQS_OFF + qg*8 + j];
      sval[0][j] = acc[0][j] + sc0 + sq;
      sval[1][j] = acc[1][j] + sc1 + sq;
    }
    #pragma unroll
    for (int i = 0; i < 2; ++i) {
      float mr = sval[i][0];
      #pragma unroll
      for (int j = 1; j < 8; ++j) mr = fmaxf(mr, sval[i][j]);
      mr = fmaxf(mr, __shfl_xor(mr, 1, 8));
      mr = fmaxf(mr, __shfl_xor(mr, 2, 8));
      mr = fmaxf(mr, __shfl_xor(mr, 4, 8));
      float sum = 0.f;
      #pragma unroll
      for (int j = 0; j < 8; ++j) { sval[i][j] = __expf(sval[i][j] - mr); sum += sval[i][j]; }
      sum += __shfl_xor(sum, 1, 8);
      sum += __shfl_xor(sum, 2, 8);
      sum += __shfl_xor(sum, 4, 8);
      const float inv = 1.0f / sum;
      if (qg == 0) m_ws[b*NC + c0 + cp*2 + i] = mr;   // rowmax for b-softmax
      #pragma unroll
      for (int j = 0; j < 8; ++j)
        lds[AT_OFF + (qg*8 + j)*68 + cp*2 + i] = sval[i][j] * inv;
    }
  }

  // ---------------- GEMM2: aq = a @ query (K=64), fused G epilogue ----------------
  const int dg = t & 31, cg = t >> 5;     // thread owns aq[8 c][4 d]
  const int swz = (lc & 7) * 4;           // XOR swizzle for qs staging
  for (int chunk = 0; chunk < 4; ++chunk) {
    const int dc0 = chunk * 128;
    __syncthreads();   // previous chunk's qs reads done; aT visible on chunk 0
    {
      const float* qrow = qry + ((size_t)(b*NQ + lc))*ND + dc0 + lj*32;
      #pragma unroll
      for (int v = 0; v < 8; ++v) {
        const float4 qv = *(const float4*)(qrow + v*4);
        const int dloc = (lj*32 + v*4) ^ swz;
        *(float4*)&lds[lc*128 + dloc] = qv;
      }
    }
    __syncthreads();
    float acc2[8][4];
    #pragma unroll
    for (int i = 0; i < 8; ++i)
      #pragma unroll
      for (int j = 0; j < 4; ++j) acc2[i][j] = 0.f;
    #pragma unroll 2
    for (int k = 0; k < 64; ++k) {
      const int dloc = (dg*4) ^ ((k & 7)*4);
      const float4 qv = *(const float4*)&lds[k*128 + dloc];
      const float4 a0 = *(const float4*)&lds[AT_OFF + k*68 + cg*8];
      const float4 a1 = *(const float4*)&lds[AT_OFF + k*68 + cg*8 + 4];
      const float av[8] = {a0.x,a0.y,a0.z,a0.w,a1.x,a1.y,a1.z,a1.w};
      #pragma unroll
      for (int i = 0; i < 8; ++i) {
        acc2[i][0] += av[i]*qv.x; acc2[i][1] += av[i]*qv.y;
        acc2[i][2] += av[i]*qv.z; acc2[i][3] += av[i]*qv.w;
      }
    }
    #pragma unroll
    for (int i = 0; i < 8; ++i) {
      const int c = c0 + cg*8 + i;
      const float4 cv = *(const float4*)(ctx + ((size_t)(b*NC + c))*ND + dc0 + dg*4);
      float* grow = G + ((size_t)(b*NC + c))*2048 + dc0 + dg*4;
      float4 aq; aq.x = acc2[i][0]; aq.y = acc2[i][1]; aq.z = acc2[i][2]; aq.w = acc2[i][3];
      float4 pr; pr.x = cv.x*aq.x; pr.y = cv.y*aq.y; pr.z = cv.z*aq.z; pr.w = cv.w*aq.w;
      *(float4*)(grow)        = cv;   // G part 0: context
      *(float4*)(grow + 512)  = aq;   // G part 1: attended_query
      *(float4*)(grow + 1024) = pr;   // G part 2: context * attended_query
    }
  }
}

// b = softmax_c(max_q S); partial weighted context sums per 32-row chunk
__global__ __launch_bounds__(256) void k2_partial(
    const float* __restrict__ ctx, const float* __restrict__ m_ws, float* __restrict__ pc)
{
  const int t  = threadIdx.x;
  const int b  = blockIdx.x >> 4;
  const int ch = blockIdx.x & 15;
  __shared__ float r8[8];
  __shared__ float wts[32];

  const float v0 = m_ws[b*NC + t];
  const float v1 = m_ws[b*NC + 256 + t];
  float mx = fmaxf(v0, v1);
  #pragma unroll
  for (int o = 32; o; o >>= 1) mx = fmaxf(mx, __shfl_xor(mx, o, 64));
  if ((t & 63) == 0) r8[t >> 6] = mx;
  __syncthreads();
  mx = fmaxf(fmaxf(r8[0], r8[1]), fmaxf(r8[2], r8[3]));
  float e = __expf(v0 - mx) + __expf(v1 - mx);
  #pragma unroll
  for (int o = 32; o; o >>= 1) e += __shfl_xor(e, o, 64);
  if ((t & 63) == 0) r8[4 + (t >> 6)] = e;
  __syncthreads();
  const float denom = r8[4] + r8[5] + r8[6] + r8[7];
  if (t < 32) wts[t] = __expf(m_ws[b*NC + ch*32 + t] - mx) / denom;
  __syncthreads();

  float s0 = 0.f, s1 = 0.f;
  const float* base = ctx + ((size_t)(b*NC + ch*32))*ND;
  for (int c = 0; c < 32; ++c) {
    const float w = wts[c];
    s0 += w * base[(size_t)c*ND + t];
    s1 += w * base[(size_t)c*ND + t + 256];
  }
  pc[((size_t)(b*16 + ch))*ND + t]       = s0;
  pc[((size_t)(b*16 + ch))*ND + t + 256] = s1;
}

__global__ __launch_bounds__(512) void k2_reduce(
    const float* __restrict__ pc, float* __restrict__ ac)
{
  const int b = blockIdx.x;
  const int d = threadIdx.x;   // 512
  float s = 0.f;
  #pragma unroll
  for (int ch = 0; ch < 16; ++ch) s += pc[((size_t)(b*16 + ch))*ND + d];
  ac[b*ND + d] = s;
}

// G part 3: context * attended_context (broadcast over c)
__global__ __launch_bounds__(256) void k3_part3(
    const float* __restrict__ ctx, const float* __restrict__ ac, float* __restrict__ G)
{
  const size_t e = ((size_t)blockIdx.x*256 + threadIdx.x) * 8;
  const int b = (int)(e >> 18);          // / (512*512)
  const int r = (int)(e & 262143);
  const int c = r >> 9;
  const int d = r & 511;
  const float4 x0 = *(const float4*)(ctx + e);
  const float4 x1 = *(const float4*)(ctx + e + 4);
  const float4 a0 = *(const float4*)(ac + b*ND + d);
  const float4 a1 = *(const float4*)(ac + b*ND + d + 4);
  float* g = G + ((size_t)(b*NC + c))*2048 + 1536 + d;
  *(float4*)(g)     = make_float4(x0.x*a0.x, x0.y*a0.y, x0.z*a0.z, x0.w*a0.w);
  *(float4*)(g + 4) = make_float4(x1.x*a1.x, x1.y*a1.y, x1.z*a1.z, x1.w*a1.w);
}

extern "C" void kernel_launch(void* const* d_in, const int* in_sizes, int n_in,
                              void* d_out, int out_size, void* d_ws, size_t ws_size,
                              hipStream_t stream)
{
  const float* ctx = (const float*)d_in[0];
  const float* qry = (const float*)d_in[1];
  const float* W   = (const float*)d_in[2];
  float* G = (float*)d_out;

  float* m_ws = (float*)d_ws;            // [32][512]
  float* pc   = m_ws + NB*NC;            // [32][16][512]
  float* ac   = pc + (size_t)NB*16*ND;   // [32][512]

  k1_main  <<<dim3(NB*8),  dim3(256), 0, stream>>>(ctx, qry, W, G, m_ws);
  k2_partial<<<dim3(NB*16), dim3(256), 0, stream>>>(ctx, m_ws, pc);
  k2_reduce<<<dim3(NB),    dim3(512), 0, stream>>>(pc, ac);
  k3_part3 <<<dim3((NB*NC*ND)/(256*8)), dim3(256), 0, stream>>>(ctx, ac, G);
}

// Round 2
// 63.298 us; speedup vs baseline: 1.4761x; 1.4761x over previous
//
#include <hip/hip_runtime.h>
#include <cstdint>

#define NB 32
#define NC 512
#define NQ 64
#define ND 512

typedef __attribute__((ext_vector_type(8))) short bf16x8;   // 8 bf16 (4 VGPRs)
typedef __attribute__((ext_vector_type(4))) float f32x4;

// LDS layout (short units, 2B). PITCH=72 shorts (144B: 16B-aligned rows, row*36 banks ≡ 4*row)
#define PITCH 72
#define P_OFF 0            // P probs bf16 [64c][72]           (persists through phase B)
#define CM_OFF 4608        // phase A: ctx*w_m bf16 [64][72]
#define QQ_OFF 9216        // phase A: query bf16 [64][72]
#define QT_OFF 4608        // phase B: query^T bf16 [64d][72q] (reuses CM)
#define AQ_F32 4608        // phase B: aq f32 [64][68], float index (short idx 9216, reuses QQ)
#define AQP 68
#define SCS_F 8960         // s_c f32[64] (float idx; short 17920)
#define SQS_F 9024         // s_q f32[64]
#define SM_SHORTS 18176    // 36352 B

__device__ __forceinline__ short f2bf(float f) {   // RNE f32 -> bf16
  union { float f; unsigned u; } v; v.f = f;
  v.u += 0x7fffu + ((v.u >> 16) & 1u);
  return (short)(v.u >> 16);
}

__global__ __launch_bounds__(256) void k1_main(
    const float* __restrict__ ctx, const float* __restrict__ qry,
    const float* __restrict__ W, float* __restrict__ G, float* __restrict__ m_ws)
{
  __shared__ __align__(16) short sm[SM_SHORTS];
  float* smf = (float*)sm;

  const int t    = threadIdx.x;
  const int lane = t & 63;
  const int w    = t >> 6;        // wave 0..3: owns c-rows w*16..w*16+15
  const int ln15 = lane & 15;
  const int g    = lane >> 4;
  const int b    = blockIdx.x >> 3;
  const int c0   = (blockIdx.x & 7) * 64;

  // streaming mapping: 16 lanes cover one contiguous 256B row segment
  const int srow = t >> 4;        // 0..15
  const int scol = (t & 15) * 4;  // 0..60

  f32x4 acc[4] = {};              // S subtiles: n = q-col block
  float scp[4] = {0,0,0,0}, sqp[4] = {0,0,0,0};

  // ---------- Phase A: S = (ctx*w_m) @ query^T via MFMA, K=512 in 8 chunks ----------
  for (int kc = 0; kc < 8; ++kc) {
    const int d0 = kc * 64;
    const float4 wc = *(const float4*)(W + d0 + scol);
    const float4 wq = *(const float4*)(W + ND + d0 + scol);
    const float4 wm = *(const float4*)(W + 2*ND + d0 + scol);
    __syncthreads();
    #pragma unroll
    for (int k4 = 0; k4 < 4; ++k4) {
      const int r = k4*16 + srow;
      const float4 cv = *(const float4*)(ctx + ((size_t)(b*NC + c0 + r))*ND + d0 + scol);
      const float4 qv = *(const float4*)(qry + ((size_t)(b*NQ + r))*ND + d0 + scol);
      scp[k4] += cv.x*wc.x + cv.y*wc.y + cv.z*wc.z + cv.w*wc.w;
      sqp[k4] += qv.x*wq.x + qv.y*wq.y + qv.z*wq.z + qv.w*wq.w;
      short4 cs; cs.x = f2bf(cv.x*wm.x); cs.y = f2bf(cv.y*wm.y);
                 cs.z = f2bf(cv.z*wm.z); cs.w = f2bf(cv.w*wm.w);
      short4 qs; qs.x = f2bf(qv.x); qs.y = f2bf(qv.y);
                 qs.z = f2bf(qv.z); qs.w = f2bf(qv.w);
      *(short4*)&sm[CM_OFF + r*PITCH + scol] = cs;
      *(short4*)&sm[QQ_OFF + r*PITCH + scol] = qs;
    }
    __syncthreads();
    #pragma unroll
    for (int kk = 0; kk < 2; ++kk) {
      const bf16x8 a = *(const bf16x8*)&sm[CM_OFF + (w*16 + ln15)*PITCH + kk*32 + g*8];
      #pragma unroll
      for (int n = 0; n < 4; ++n) {
        const bf16x8 bq = *(const bf16x8*)&sm[QQ_OFF + (n*16 + ln15)*PITCH + kk*32 + g*8];
        acc[n] = __builtin_amdgcn_mfma_f32_16x16x32_bf16(a, bq, acc[n], 0, 0, 0);
      }
    }
  }

  // s_c / s_q: reduce each owned row across its 16 lanes
  #pragma unroll
  for (int k4 = 0; k4 < 4; ++k4) {
    float v = scp[k4], u = sqp[k4];
    v += __shfl_xor(v, 1, 16); v += __shfl_xor(v, 2, 16);
    v += __shfl_xor(v, 4, 16); v += __shfl_xor(v, 8, 16);
    u += __shfl_xor(u, 1, 16); u += __shfl_xor(u, 2, 16);
    u += __shfl_xor(u, 4, 16); u += __shfl_xor(u, 8, 16);
    if (ln15 == 0) { smf[SCS_F + k4*16 + srow] = v; smf[SQS_F + k4*16 + srow] = u; }
  }
  __syncthreads();

  // ---------- softmax over q (C/D layout: col q = ln15+16n, row c = w*16+g*4+reg) ----------
  #pragma unroll
  for (int reg = 0; reg < 4; ++reg) {
    const int rloc = w*16 + g*4 + reg;
    const float sc = smf[SCS_F + rloc];
    float sv[4];
    #pragma unroll
    for (int n = 0; n < 4; ++n) sv[n] = acc[n][reg] + sc + smf[SQS_F + ln15 + 16*n];
    float mx = fmaxf(fmaxf(sv[0], sv[1]), fmaxf(sv[2], sv[3]));
    mx = fmaxf(mx, __shfl_xor(mx, 1, 16));
    mx = fmaxf(mx, __shfl_xor(mx, 2, 16));
    mx = fmaxf(mx, __shfl_xor(mx, 4, 16));
    mx = fmaxf(mx, __shfl_xor(mx, 8, 16));
    float s = 0.f;
    #pragma unroll
    for (int n = 0; n < 4; ++n) { sv[n] = __expf(sv[n] - mx); s += sv[n]; }
    s += __shfl_xor(s, 1, 16); s += __shfl_xor(s, 2, 16);
    s += __shfl_xor(s, 4, 16); s += __shfl_xor(s, 8, 16);
    const float inv = 1.0f / s;
    if (ln15 == 0) m_ws[b*NC + c0 + rloc] = mx;
    #pragma unroll
    for (int n = 0; n < 4; ++n)
      sm[P_OFF + rloc*PITCH + ln15 + 16*n] = f2bf(sv[n] * inv);
  }

  // ---------- Phase B: aq = P @ query (K=64), fused epilogue parts 0,1,2 ----------
  float* aqf = smf + AQ_F32;
  for (int dc = 0; dc < 8; ++dc) {
    const int d0 = dc * 64;
    __syncthreads();
    // stage qT[dd][q] bf16, XOR-swizzle q by (dd>>4)*8 to spread banks
    #pragma unroll
    for (int k4 = 0; k4 < 4; ++k4) {
      const int q = k4*16 + srow;
      const float4 qv = *(const float4*)(qry + ((size_t)(b*NQ + q))*ND + d0 + scol);
      sm[QT_OFF + (scol+0)*PITCH + (q ^ (((scol+0)>>4)*8))] = f2bf(qv.x);
      sm[QT_OFF + (scol+1)*PITCH + (q ^ (((scol+1)>>4)*8))] = f2bf(qv.y);
      sm[QT_OFF + (scol+2)*PITCH + (q ^ (((scol+2)>>4)*8))] = f2bf(qv.z);
      sm[QT_OFF + (scol+3)*PITCH + (q ^ (((scol+3)>>4)*8))] = f2bf(qv.w);
    }
    __syncthreads();
    f32x4 acc2[4] = {};
    #pragma unroll
    for (int kk = 0; kk < 2; ++kk) {
      const bf16x8 a = *(const bf16x8*)&sm[P_OFF + (w*16 + ln15)*PITCH + kk*32 + g*8];
      #pragma unroll
      for (int n = 0; n < 4; ++n) {
        const bf16x8 bq = *(const bf16x8*)&sm[QT_OFF + (n*16 + ln15)*PITCH + ((kk*32 + g*8) ^ (n*8))];
        acc2[n] = __builtin_amdgcn_mfma_f32_16x16x32_bf16(a, bq, acc2[n], 0, 0, 0);
      }
    }
    // spill accumulator to LDS so stores can be full 256B row segments
    #pragma unroll
    for (int n = 0; n < 4; ++n)
      #pragma unroll
      for (int reg = 0; reg < 4; ++reg)
        aqf[(w*16 + g*4 + reg)*AQP + ln15 + 16*n] = acc2[n][reg];
    __syncthreads();
    #pragma unroll
    for (int k4 = 0; k4 < 4; ++k4) {
      const int r = k4*16 + srow;
      const float4 aq4 = *(const float4*)&aqf[r*AQP + scol];
      const float4 cv  = *(const float4*)(ctx + ((size_t)(b*NC + c0 + r))*ND + d0 + scol);
      float* gp = G + ((size_t)(b*NC + c0 + r))*2048 + d0 + scol;
      *(float4*)(gp)        = cv;                                            // part 0
      *(float4*)(gp + 512)  = aq4;                                           // part 1
      *(float4*)(gp + 1024) = make_float4(cv.x*aq4.x, cv.y*aq4.y,
                                          cv.z*aq4.z, cv.w*aq4.w);           // part 2
    }
  }
}

// b = softmax_c(max_q S); partial weighted context sums per 32-row chunk
__global__ __launch_bounds__(256) void k2_partial(
    const float* __restrict__ ctx, const float* __restrict__ m_ws, float* __restrict__ pc)
{
  const int t  = threadIdx.x;
  const int b  = blockIdx.x >> 4;
  const int ch = blockIdx.x & 15;
  __shared__ float r8[8];
  __shared__ float wts[32];

  const float v0 = m_ws[b*NC + t];
  const float v1 = m_ws[b*NC + 256 + t];
  float mx = fmaxf(v0, v1);
  #pragma unroll
  for (int o = 32; o; o >>= 1) mx = fmaxf(mx, __shfl_xor(mx, o, 64));
  if ((t & 63) == 0) r8[t >> 6] = mx;
  __syncthreads();
  mx = fmaxf(fmaxf(r8[0], r8[1]), fmaxf(r8[2], r8[3]));
  float e = __expf(v0 - mx) + __expf(v1 - mx);
  #pragma unroll
  for (int o = 32; o; o >>= 1) e += __shfl_xor(e, o, 64);
  if ((t & 63) == 0) r8[4 + (t >> 6)] = e;
  __syncthreads();
  const float denom = r8[4] + r8[5] + r8[6] + r8[7];
  if (t < 32) wts[t] = __expf(m_ws[b*NC + ch*32 + t] - mx) / denom;
  __syncthreads();

  float s0 = 0.f, s1 = 0.f;
  const float* base = ctx + ((size_t)(b*NC + ch*32))*ND;
  for (int c = 0; c < 32; ++c) {
    const float w = wts[c];
    s0 += w * base[(size_t)c*ND + t];
    s1 += w * base[(size_t)c*ND + t + 256];
  }
  pc[((size_t)(b*16 + ch))*ND + t]       = s0;
  pc[((size_t)(b*16 + ch))*ND + t + 256] = s1;
}

__global__ __launch_bounds__(512) void k2_reduce(
    const float* __restrict__ pc, float* __restrict__ ac)
{
  const int b = blockIdx.x;
  const int d = threadIdx.x;   // 512
  float s = 0.f;
  #pragma unroll
  for (int ch = 0; ch < 16; ++ch) s += pc[((size_t)(b*16 + ch))*ND + d];
  ac[b*ND + d] = s;
}

// G part 3: context * attended_context (broadcast over c)
__global__ __launch_bounds__(256) void k3_part3(
    const float* __restrict__ ctx, const float* __restrict__ ac, float* __restrict__ G)
{
  const size_t e = ((size_t)blockIdx.x*256 + threadIdx.x) * 8;
  const int b = (int)(e >> 18);          // / (512*512)
  const int r = (int)(e & 262143);
  const int c = r >> 9;
  const int d = r & 511;
  const float4 x0 = *(const float4*)(ctx + e);
  const float4 x1 = *(const float4*)(ctx + e + 4);
  const float4 a0 = *(const float4*)(ac + b*ND + d);
  const float4 a1 = *(const float4*)(ac + b*ND + d + 4);
  float* g = G + ((size_t)(b*NC + c))*2048 + 1536 + d;
  *(float4*)(g)     = make_float4(x0.x*a0.x, x0.y*a0.y, x0.z*a0.z, x0.w*a0.w);
  *(float4*)(g + 4) = make_float4(x1.x*a1.x, x1.y*a1.y, x1.z*a1.z, x1.w*a1.w);
}

extern "C" void kernel_launch(void* const* d_in, const int* in_sizes, int n_in,
                              void* d_out, int out_size, void* d_ws, size_t ws_size,
                              hipStream_t stream)
{
  const float* ctx = (const float*)d_in[0];
  const float* qry = (const float*)d_in[1];
  const float* W   = (const float*)d_in[2];
  float* G = (float*)d_out;

  float* m_ws = (float*)d_ws;            // [32][512]
  float* pc   = m_ws + NB*NC;            // [32][16][512]
  float* ac   = pc + (size_t)NB*16*ND;   // [32][512]

  k1_main   <<<dim3(NB*8),  dim3(256), 0, stream>>>(ctx, qry, W, G, m_ws);
  k2_partial<<<dim3(NB*16), dim3(256), 0, stream>>>(ctx, m_ws, pc);
  k2_reduce <<<dim3(NB),    dim3(512), 0, stream>>>(pc, ac);
  k3_part3  <<<dim3((NB*NC*ND)/(256*8)), dim3(256), 0, stream>>>(ctx, ac, G);
}